// Round 1
// baseline (112.245 us; speedup 1.0000x reference)
//
#include <hip/hip_runtime.h>
#include <math.h>

#define B_N   2
#define A_N   180
#define HR_N  512
#define H_OUT 512
#define W_OUT 512
#define PAD   51          // int(0.1 * 512)
#define HP    614         // H_OUT + 2*PAD
#define WP    614

// Workspace layout (floats): col[A_N][B_N][HP], then ct[A_N], st[A_N]

__global__ void prep_kernel(const float* __restrict__ sino,
                            const float* __restrict__ angles,
                            float* __restrict__ col,
                            float* __restrict__ trig) {
    int idx = blockIdx.x * blockDim.x + threadIdx.x;
    if (idx < A_N) {
        float th = -angles[idx] * (float)(M_PI / 180.0);
        trig[idx]        = cosf(th);
        trig[A_N + idx]  = sinf(th);
    }
    const int total = A_N * B_N * HP;
    if (idx < total) {
        int h = idx % HP;
        int t = idx / HP;
        int b = t % B_N;
        int a = t / B_N;
        float src = ((float)h + 0.5f) * ((float)HR_N / (float)HP) - 0.5f;
        src = fminf(fmaxf(src, 0.0f), (float)(HR_N - 1));
        int i0 = (int)floorf(src);
        int i1 = min(i0 + 1, HR_N - 1);
        float wH = src - (float)i0;
        const float* srow = sino + ((size_t)b * A_N + a) * HR_N;
        col[idx] = srow[i0] * (1.0f - wH) + srow[i1] * wH;
    }
}

__global__ __launch_bounds__(256) void bp_kernel(const float* __restrict__ col,
                                                 const float* __restrict__ trig,
                                                 float* __restrict__ out) {
    __shared__ float s_ct[A_N];
    __shared__ float s_st[A_N];
    int t = threadIdx.x;
    if (t < A_N) {
        s_ct[t] = trig[t];
        s_st[t] = trig[A_N + t];
    }
    __syncthreads();

    int idx = blockIdx.x * blockDim.x + t;        // 0 .. 512*512-1
    int w = idx & (W_OUT - 1);
    int h = idx >> 9;                             // /512
    int hp = h + PAD;
    int wp = w + PAD;
    float xw = ((float)wp + 0.5f) * (2.0f / (float)WP) - 1.0f;
    float yh = ((float)hp + 0.5f) * (2.0f / (float)HP) - 1.0f;

    float acc0 = 0.0f, acc1 = 0.0f;

    for (int a = 0; a < A_N; ++a) {
        float c = s_ct[a];
        float s = s_st[a];
        float gx = c * xw - s * yh;
        float gy = s * xw + c * yh;
        float ix = (gx * (float)WP + ((float)WP - 1.0f)) * 0.5f;
        float iy = (gy * (float)HP + ((float)HP - 1.0f)) * 0.5f;

        // x contributes only a weight factor (projection constant along x)
        float x0f = floorf(ix);
        float wx  = ix - x0f;
        float xfac = 0.0f;
        if (x0f >= 0.0f && x0f <= (float)(WP - 1)) xfac += (1.0f - wx);   // x0 valid
        if (x0f >= -1.0f && x0f <= (float)(WP - 2)) xfac += wx;           // x1 valid

        float y0f = floorf(iy);
        float wy  = iy - y0f;
        int y0 = (int)y0f;
        int y1 = y0 + 1;
        int y0c = min(max(y0, 0), HP - 1);
        int y1c = min(max(y1, 0), HP - 1);
        float w0 = (y0 >= 0 && y0 <= HP - 1) ? (1.0f - wy) : 0.0f;
        float w1 = (y1 >= 0 && y1 <= HP - 1) ? wy          : 0.0f;

        const float* cb = col + (size_t)a * (B_N * HP);
        float v0 = w0 * cb[y0c]      + w1 * cb[y1c];
        float v1 = w0 * cb[HP + y0c] + w1 * cb[HP + y1c];
        acc0 += xfac * v0;
        acc1 += xfac * v1;
    }

    const float inv = 1.0f / (180.0f + 1e-6f);
    out[idx] = acc0 * inv;
    out[(size_t)(H_OUT * W_OUT) + idx] = acc1 * inv;
}

extern "C" void kernel_launch(void* const* d_in, const int* in_sizes, int n_in,
                              void* d_out, int out_size, void* d_ws, size_t ws_size,
                              hipStream_t stream) {
    const float* sino   = (const float*)d_in[0];
    const float* angles = (const float*)d_in[1];
    float* ws   = (float*)d_ws;
    float* col  = ws;                          // A_N * B_N * HP floats
    float* trig = ws + (size_t)A_N * B_N * HP; // 2 * A_N floats

    const int total = A_N * B_N * HP;
    prep_kernel<<<(total + 255) / 256, 256, 0, stream>>>(sino, angles, col, trig);

    const int npix = H_OUT * W_OUT;
    bp_kernel<<<npix / 256, 256, 0, stream>>>(col, trig, (float*)d_out);
}

// Round 2
// 107.185 us; speedup vs baseline: 1.0472x; 1.0472x over previous
//
#include <hip/hip_runtime.h>
#include <math.h>

#define B_N   2
#define A_N   180
#define HR_N  512
#define H_OUT 512
#define W_OUT 512
#define PAD   51            // int(0.1 * 512)
#define HP    614           // H_OUT + 2*PAD
#define WP    614
#define GUARD 64            // zero guard each side (max excursion iy in [-56.3, 669.3])
#define HPP   (HP + 2*GUARD)   // 742 floats per (a,b) column

// Workspace layout (floats):
//   colp[A_N][B_N][HPP]  zero-padded resampled sinogram columns
//   tg[2*A_N]            interleaved {cos, sin} per angle

__global__ void prep_kernel(const float* __restrict__ sino,
                            const float* __restrict__ angles,
                            float* __restrict__ colp,
                            float* __restrict__ tg) {
    int idx = blockIdx.x * blockDim.x + threadIdx.x;
    if (idx < A_N) {
        float th = -angles[idx] * (float)(M_PI / 180.0);
        tg[2 * idx]     = cosf(th);
        tg[2 * idx + 1] = sinf(th);
    }
    const int total = A_N * B_N * HPP;
    if (idx < total) {
        int y = idx % HPP;
        int t = idx / HPP;
        int b = t & 1;
        int a = t >> 1;
        int yy = y - GUARD;
        float v = 0.0f;
        if (yy >= 0 && yy < HP) {
            float src = ((float)yy + 0.5f) * ((float)HR_N / (float)HP) - 0.5f;
            src = fminf(fmaxf(src, 0.0f), (float)(HR_N - 1));
            int i0 = (int)floorf(src);
            int i1 = min(i0 + 1, HR_N - 1);
            float wH = src - (float)i0;
            const float* srow = sino + ((size_t)b * A_N + a) * HR_N;
            v = srow[i0] * (1.0f - wH) + srow[i1] * wH;
        }
        colp[idx] = v;
    }
}

__global__ __launch_bounds__(256) void bp_kernel(const float* __restrict__ colp,
                                                 const float* __restrict__ tg,
                                                 float* __restrict__ out) {
    __shared__ float s_tg[2 * A_N];
    int t = threadIdx.x;
    for (int i = t; i < 2 * A_N; i += 256) s_tg[i] = tg[i];
    __syncthreads();

    int idx = blockIdx.x * blockDim.x + t;        // 0 .. 512*512-1
    int w = idx & (W_OUT - 1);
    int h = idx >> 9;
    // ix = c*X - s*Y + 306.5 ; iy = s*X + c*Y + 306.5  (WP == HP == 614)
    float X = (float)w - 255.5f;
    float Y = (float)h - 255.5f;

    float acc0 = 0.0f, acc1 = 0.0f;

#pragma unroll 4
    for (int a = 0; a < A_N; ++a) {
        float c = s_tg[2 * a];
        float s = s_tg[2 * a + 1];
        float ix = fmaf(c, X, fmaf(-s, Y, 306.5f));
        float iy = fmaf(s, X, fmaf(c, Y, 306.5f));

        // x contributes only a weight: 1 in the interior, linear ramps at the
        // borders, 0 outside:  clamp(ix+1,0,1) * clamp(WP-ix,0,1)
        float xfac = fminf(fmaxf(ix + 1.0f, 0.0f), 1.0f)
                   * fminf(fmaxf((float)WP - ix, 0.0f), 1.0f);

        float y0f = floorf(iy);
        float wy  = iy - y0f;
        int   y0  = (int)y0f;

        const float* cb = colp + (size_t)a * (B_N * HPP) + GUARD + y0;
        float c00 = cb[0];
        float c01 = cb[1];
        float c10 = cb[HPP];
        float c11 = cb[HPP + 1];

        acc0 = fmaf(xfac, fmaf(wy, c01 - c00, c00), acc0);
        acc1 = fmaf(xfac, fmaf(wy, c11 - c10, c10), acc1);
    }

    const float inv = 1.0f / (180.0f + 1e-6f);
    out[idx] = acc0 * inv;
    out[(size_t)(H_OUT * W_OUT) + idx] = acc1 * inv;
}

extern "C" void kernel_launch(void* const* d_in, const int* in_sizes, int n_in,
                              void* d_out, int out_size, void* d_ws, size_t ws_size,
                              hipStream_t stream) {
    const float* sino   = (const float*)d_in[0];
    const float* angles = (const float*)d_in[1];
    float* ws   = (float*)d_ws;
    float* colp = ws;                            // A_N * B_N * HPP floats
    float* tg   = ws + (size_t)A_N * B_N * HPP;  // 2 * A_N floats

    const int total = A_N * B_N * HPP;
    prep_kernel<<<(total + 255) / 256, 256, 0, stream>>>(sino, angles, colp, tg);

    const int npix = H_OUT * W_OUT;
    bp_kernel<<<npix / 256, 256, 0, stream>>>(colp, tg, (float*)d_out);
}

// Round 3
// 89.994 us; speedup vs baseline: 1.2473x; 1.1910x over previous
//
#include <hip/hip_runtime.h>
#include <math.h>

#define B_N   2
#define A_N   180
#define HR_N  512
#define H_OUT 512
#define W_OUT 512
#define PAD   51            // int(0.1 * 512)
#define HP    614           // H_OUT + 2*PAD
#define WP    614
#define GUARD 64            // zero guard each side (iy in [-56.3, 669.3])
#define HPP   (HP + 2*GUARD)   // 742
#define NPIX  (H_OUT * W_OUT)
#define HALF_A (A_N / 2)    // 90

// Workspace layout (floats):
//   pk[A_N][HPP] float4: {b0[y], b1[y], b0[y+1], b1[y+1]}  (guarded, zero outside)
//   tg[2*A_N]   interleaved {cos, sin}

__device__ __forceinline__ float col_val(const float* __restrict__ sino,
                                         int b, int a, int yy) {
    // resampled sinogram column value at guard-relative row yy (may be OOB -> 0)
    if (yy < 0 || yy >= HP) return 0.0f;
    float src = ((float)yy + 0.5f) * ((float)HR_N / (float)HP) - 0.5f;
    src = fminf(fmaxf(src, 0.0f), (float)(HR_N - 1));
    int i0 = (int)floorf(src);
    int i1 = min(i0 + 1, HR_N - 1);
    float wH = src - (float)i0;
    const float* srow = sino + ((size_t)b * A_N + a) * HR_N;
    return srow[i0] * (1.0f - wH) + srow[i1] * wH;
}

__global__ void prep_kernel(const float* __restrict__ sino,
                            const float* __restrict__ angles,
                            float4* __restrict__ pk,
                            float* __restrict__ tg) {
    int idx = blockIdx.x * blockDim.x + threadIdx.x;
    if (idx < A_N) {
        float th = -angles[idx] * (float)(M_PI / 180.0);
        tg[2 * idx]     = cosf(th);
        tg[2 * idx + 1] = sinf(th);
    }
    const int total = A_N * HPP;
    if (idx < total) {
        int y = idx % HPP;
        int a = idx / HPP;
        int yy = y - GUARD;
        float4 v;
        v.x = col_val(sino, 0, a, yy);
        v.y = col_val(sino, 1, a, yy);
        v.z = col_val(sino, 0, a, yy + 1);
        v.w = col_val(sino, 1, a, yy + 1);
        pk[idx] = v;
    }
}

__global__ __launch_bounds__(256) void bp_kernel(const float4* __restrict__ pk,
                                                 const float* __restrict__ tg,
                                                 float* __restrict__ out) {
    __shared__ float s_tg[2 * HALF_A];
    int t = threadIdx.x;
    int half = blockIdx.y;
    if (t < 2 * HALF_A) s_tg[t] = tg[half * (2 * HALF_A) + t];
    __syncthreads();

    int idx = blockIdx.x * blockDim.x + t;        // 0 .. NPIX-1
    int w = idx & (W_OUT - 1);
    int h = idx >> 9;
    // ix = c*X - s*Y + 306.5 ; iy = s*X + c*Y + 306.5  (WP == HP == 614)
    float X = (float)w - 255.5f;
    float Y = (float)h - 255.5f;

    float acc0 = 0.0f, acc1 = 0.0f;

    const float4* pkh = pk + (size_t)(half * HALF_A) * HPP + GUARD;

#pragma unroll 6
    for (int a = 0; a < HALF_A; ++a) {
        float c = s_tg[2 * a];
        float s = s_tg[2 * a + 1];
        float ix = fmaf(c, X, fmaf(-s, Y, 306.5f));
        float iy = fmaf(s, X, fmaf(c, Y, 306.5f));

        // x contributes only a weight: clamp(ix+1,0,1) * clamp(WP-ix,0,1)
        float xfac = fminf(fmaxf(ix + 1.0f, 0.0f), 1.0f)
                   * fminf(fmaxf((float)WP - ix, 0.0f), 1.0f);

        float y0f = floorf(iy);
        float wy  = iy - y0f;
        int   y0  = (int)y0f;

        float4 cv = pkh[(size_t)a * HPP + y0];
        acc0 = fmaf(xfac, fmaf(wy, cv.z - cv.x, cv.x), acc0);
        acc1 = fmaf(xfac, fmaf(wy, cv.w - cv.y, cv.y), acc1);
    }

    const float inv = 1.0f / (180.0f + 1e-6f);
    atomicAdd(&out[idx],        acc0 * inv);
    atomicAdd(&out[NPIX + idx], acc1 * inv);
}

extern "C" void kernel_launch(void* const* d_in, const int* in_sizes, int n_in,
                              void* d_out, int out_size, void* d_ws, size_t ws_size,
                              hipStream_t stream) {
    const float* sino   = (const float*)d_in[0];
    const float* angles = (const float*)d_in[1];
    float* ws   = (float*)d_ws;
    float4* pk  = (float4*)ws;                       // A_N * HPP float4
    float* tg   = ws + (size_t)4 * A_N * HPP;        // 2 * A_N floats

    const int total = A_N * HPP;
    prep_kernel<<<(total + 255) / 256, 256, 0, stream>>>(sino, angles, pk, tg);

    hipMemsetAsync(d_out, 0, (size_t)out_size * sizeof(float), stream);

    dim3 grid(NPIX / 256, 2);
    bp_kernel<<<grid, 256, 0, stream>>>(pk, tg, (float*)d_out);
}

// Round 4
// 87.254 us; speedup vs baseline: 1.2864x; 1.0314x over previous
//
#include <hip/hip_runtime.h>
#include <math.h>

#define B_N   2
#define A_N   180
#define HR_N  512
#define H_OUT 512
#define W_OUT 512
#define PAD   51               // int(0.1 * 512)
#define HP    614              // H_OUT + 2*PAD
#define WP    614
#define GUARD 80               // zero guard each side (staged yy in [24, 749])
#define HPP   (HP + 2*GUARD)   // 774
#define NPIX  (H_OUT * W_OUT)

#define TILE   16              // 16x16 pixel tiles, 256 threads
#define CH     30              // angles per LDS chunk
#define NCH    (A_N / CH)      // 6
#define WIN    24              // float4 window entries per angle per tile

// Workspace (floats):
//   pk[A_N][HPP] float4: {b0[y], b1[y], b0[y+1], b1[y+1]}  (zero-guarded)
//   tg[2*A_N]   interleaved {cos, sin}

__device__ __forceinline__ float col_val(const float* __restrict__ sino,
                                         int b, int a, int yy) {
    if (yy < 0 || yy >= HP) return 0.0f;
    float src = ((float)yy + 0.5f) * ((float)HR_N / (float)HP) - 0.5f;
    src = fminf(fmaxf(src, 0.0f), (float)(HR_N - 1));
    int i0 = (int)floorf(src);
    int i1 = min(i0 + 1, HR_N - 1);
    float wH = src - (float)i0;
    const float* srow = sino + ((size_t)b * A_N + a) * HR_N;
    return srow[i0] * (1.0f - wH) + srow[i1] * wH;
}

__global__ void prep_kernel(const float* __restrict__ sino,
                            const float* __restrict__ angles,
                            float4* __restrict__ pk,
                            float* __restrict__ tg) {
    int idx = blockIdx.x * blockDim.x + threadIdx.x;
    if (idx < A_N) {
        float th = -angles[idx] * (float)(M_PI / 180.0);
        tg[2 * idx]     = cosf(th);
        tg[2 * idx + 1] = sinf(th);
    }
    const int total = A_N * HPP;
    if (idx < total) {
        int y = idx % HPP;
        int a = idx / HPP;
        int yy = y - GUARD;
        float4 v;
        v.x = col_val(sino, 0, a, yy);
        v.y = col_val(sino, 1, a, yy);
        v.z = col_val(sino, 0, a, yy + 1);
        v.w = col_val(sino, 1, a, yy + 1);
        pk[idx] = v;
    }
}

__global__ __launch_bounds__(256) void bp_kernel(const float4* __restrict__ pk,
                                                 const float* __restrict__ tg,
                                                 float* __restrict__ out) {
    __shared__ float4 s_ang[A_N];      // {c, s, (float)base, 0}
    __shared__ int    s_base[A_N];
    __shared__ float4 s_win[CH * WIN]; // staged windows for one chunk

    int t  = threadIdx.x;
    int tx = blockIdx.x, ty = blockIdx.y;

    // Per-angle setup: trig + window base for this tile
    if (t < A_N) {
        float c = tg[2 * t];
        float s = tg[2 * t + 1];
        float Xc = (float)(tx * TILE) - 248.0f;   // tile-center X (= +7.5 - 255.5)
        float Yc = (float)(ty * TILE) - 248.0f;
        float iyc = fmaf(s, Xc, fmaf(c, Yc, 306.5f));
        int base = (int)floorf(iyc) - 11;          // window covers [base, base+23]
        s_ang[t]  = make_float4(c, s, (float)base, 0.0f);
        s_base[t] = base;
    }

    int lx = t & (TILE - 1);
    int ly = t >> 4;
    int w = tx * TILE + lx;
    int h = ty * TILE + ly;
    float X = (float)w - 255.5f;
    float Y = (float)h - 255.5f;

    float acc0 = 0.0f, acc1 = 0.0f;
    __syncthreads();

    for (int ch = 0; ch < NCH; ++ch) {
        int a0 = ch * CH;
        // Stage CH angle-windows (contiguous 24-float4 runs) into LDS
        for (int e = t; e < CH * WIN; e += 256) {
            int la = e / WIN;
            int j  = e - la * WIN;
            int a  = a0 + la;
            int yy = s_base[a] + j + GUARD;        // in [24, 749] ⊂ [0, HPP)
            s_win[e] = pk[(size_t)a * HPP + yy];
        }
        __syncthreads();

#pragma unroll 6
        for (int la = 0; la < CH; ++la) {
            float4 ang = s_ang[a0 + la];           // broadcast read
            float c = ang.x, s = ang.y, fb = ang.z;
            float ix = fmaf(c, X, fmaf(-s, Y, 306.5f));
            float iy = fmaf(s, X, fmaf(c, Y, 306.5f));

            float xfac = fminf(fmaxf(ix + 1.0f, 0.0f), 1.0f)
                       * fminf(fmaxf((float)WP - ix, 0.0f), 1.0f);

            float f  = iy - fb;                    // in (0, 23): in-window by design
            int   li = (int)f;
            float wy = f - (float)li;

            float4 cv = s_win[la * WIN + li];
            acc0 = fmaf(xfac, fmaf(wy, cv.z - cv.x, cv.x), acc0);
            acc1 = fmaf(xfac, fmaf(wy, cv.w - cv.y, cv.y), acc1);
        }
        __syncthreads();
    }

    const float inv = 1.0f / (180.0f + 1e-6f);
    int idx = h * W_OUT + w;
    out[idx]        = acc0 * inv;
    out[NPIX + idx] = acc1 * inv;
}

extern "C" void kernel_launch(void* const* d_in, const int* in_sizes, int n_in,
                              void* d_out, int out_size, void* d_ws, size_t ws_size,
                              hipStream_t stream) {
    const float* sino   = (const float*)d_in[0];
    const float* angles = (const float*)d_in[1];
    float* ws   = (float*)d_ws;
    float4* pk  = (float4*)ws;                       // A_N * HPP float4
    float* tg   = ws + (size_t)4 * A_N * HPP;        // 2 * A_N floats

    const int total = A_N * HPP;
    prep_kernel<<<(total + 255) / 256, 256, 0, stream>>>(sino, angles, pk, tg);

    dim3 grid(W_OUT / TILE, H_OUT / TILE);           // 32 x 32 tiles
    bp_kernel<<<grid, 256, 0, stream>>>(pk, tg, (float*)d_out);
}